// Round 6
// baseline (221.620 us; speedup 1.0000x reference)
//
#include <hip/hip_runtime.h>
#include <stdint.h>

#define WIN 7
#define OUT_W 126
#define OUT_H 16
#define IN_W 132    // OUT_W + 6
#define IN_H 22     // OUT_H + 6
#define PITCH 140   // packed words/row; %4==0 (b128 align), 140%32=12 -> 2-way banks (free)
#define AELEM (OUT_H * PITCH)   // 2240 words per packed array
#define H 384
#define W 384
#define OH 378
#define OW 378
#define NIMG 128
#define TX 3        // 3*126 = 378 exactly
#define TY 24       // 23*16=368, last tile 10 valid rows
#define NBLK (TX * TY * NIMG)   // 9216

__device__ __forceinline__ float wave_reduce(float v) {
#pragma unroll
    for (int off = 32; off > 0; off >>= 1) v += __shfl_down(v, off, 64);
    return v;
}

// Truncate-pack two f32 into bf16 pair (lo in low 16, hi in high 16).
// Legal ONLY for centered stats: all cancellation-prone SSIM terms are
// shift-invariant and computed directly from small centered sums (R5 failed
// because raw sums cancel 1600-1200; centered ones don't).
__device__ __forceinline__ uint32_t pack2(float lo, float hi) {
    return (__builtin_bit_cast(uint32_t, hi) & 0xFFFF0000u) |
           (__builtin_bit_cast(uint32_t, lo) >> 16);
}
__device__ __forceinline__ float unpk_lo(uint32_t w) {
    return __builtin_bit_cast(float, w << 16);
}
__device__ __forceinline__ float unpk_hi(uint32_t w) {
    return __builtin_bit_cast(float, w & 0xFFFF0000u);
}

__global__ __launch_bounds__(256, 6) void ssim_main(const float* __restrict__ pred,
                                                    const float* __restrict__ act,
                                                    float* __restrict__ partials) {
    // Two packed arrays: P1=(Sx',Sy'), P2=(Sq',Sxy') of CENTERED sums. 17.9 KB.
    __shared__ __align__(16) uint32_t P[2 * AELEM];
    __shared__ float red[4];

    const int t = threadIdx.x;
    const int x0 = blockIdx.x * OUT_W;
    const int y0 = blockIdx.y * OUT_H;
    const size_t base = (size_t)blockIdx.z * H * W;

    // ---------- vertical pass: centered inputs, sliding 7-row sums ----------
    if (t < IN_W) {
        const int col = x0 + t;                       // <= 383 always
        const float* xc = pred + base + col;
        const float* yc = act + base + col;
        float xv[IN_H], yv[IN_H];
#pragma unroll
        for (int i = 0; i < IN_H; ++i) {
            const int row = y0 + i;
            const bool ok = row < H;                  // only last y-tile clips
            xv[i] = ok ? (xc[(size_t)row * W] - 0.5f) : 0.f;
            yv[i] = ok ? (yc[(size_t)row * W] - 0.5f) : 0.f;
        }
        float sx = 0.f, sy = 0.f, sq = 0.f, sxy = 0.f;
#pragma unroll
        for (int k = 0; k < WIN; ++k) {
            sx += xv[k];
            sy += yv[k];
            sq = fmaf(xv[k], xv[k], fmaf(yv[k], yv[k], sq));
            sxy = fmaf(xv[k], yv[k], sxy);
        }
        P[t] = pack2(sx, sy);
        P[AELEM + t] = pack2(sq, sxy);
#pragma unroll
        for (int r = 1; r < OUT_H; ++r) {
            const float xn = xv[r + 6], yn = yv[r + 6];
            const float xo = xv[r - 1], yo = yv[r - 1];
            sx += xn - xo;
            sy += yn - yo;
            sq = fmaf(xn, xn, fmaf(yn, yn, fmaf(-xo, xo, fmaf(-yo, yo, sq))));
            sxy = fmaf(xn, yn, fmaf(-xo, yo, sxy));
            const int a = r * PITCH + t;
            P[a] = pack2(sx, sy);
            P[AELEM + a] = pack2(sq, sxy);
        }
    }
    __syncthreads();

    // ---------- horizontal pass: packed b128 loads + register sliding ----------
    const int r = t & 15;        // tile row (all 16 used)
    const int g = t >> 4;        // column group; outputs g*8 .. g*8+7
    const int c0 = g * 8;        // quad-aligned; words c0..c0+15 <= 135 < PITCH

    const float C1B = 0.2401f;   // C1 * 49^2
    const float C2B = 2.1168f;   // C2 * 48*49

    float acc = 0.f;
    if (y0 + r < OH) {
        float S[4][8];
#pragma unroll
        for (int a = 0; a < 2; ++a) {
            const uint32_t* bp = &P[a * AELEM + r * PITCH + c0];
            uint32_t w[16];
#pragma unroll
            for (int k = 0; k < 4; ++k) {
                const uint4 q = ((const uint4*)bp)[k];
                w[4 * k + 0] = q.x; w[4 * k + 1] = q.y;
                w[4 * k + 2] = q.z; w[4 * k + 3] = q.w;
            }
            float vlo[16], vhi[16];
#pragma unroll
            for (int k = 0; k < 16; ++k) { vlo[k] = unpk_lo(w[k]); vhi[k] = unpk_hi(w[k]); }
            float slo = ((vlo[0] + vlo[1]) + (vlo[2] + vlo[3])) + ((vlo[4] + vlo[5]) + vlo[6]);
            float shi = ((vhi[0] + vhi[1]) + (vhi[2] + vhi[3])) + ((vhi[4] + vhi[5]) + vhi[6]);
            S[2 * a][0] = slo;
            S[2 * a + 1][0] = shi;
#pragma unroll
            for (int j = 1; j < 8; ++j) {
                slo += vlo[j + 6] - vlo[j - 1];
                shi += vhi[j + 6] - vhi[j - 1];
                S[2 * a][j] = slo;
                S[2 * a + 1][j] = shi;
            }
        }
        const int nmax = OUT_W - c0;      // 8 for groups 0..14, 6 for group 15
#pragma unroll
        for (int j = 0; j < 8; ++j) {
            const float Sxc = S[0][j], Syc = S[1][j];   // centered sums
            const float Sqc = S[2][j], Sxyc = S[3][j];
            // shift-invariant covariance terms (exact in centered form):
            const float pc = Sxc * Syc;
            const float qc = fmaf(Sxc, Sxc, Syc * Syc);
            const float n2 = fmaf(98.f, Sxyc, fmaf(-2.f, pc, C2B));
            const float d2 = fmaf(49.f, Sqc, C2B - qc);
            // mean terms need raw sums (exact reconstruction, no cancellation):
            const float Sx = Sxc + 24.5f, Sy = Syc + 24.5f;
            const float n1 = fmaf(2.f, Sx * Sy, C1B);
            const float d1 = fmaf(Sx, Sx, fmaf(Sy, Sy, C1B));
            const float s = (n1 * n2) * __builtin_amdgcn_rcpf(d1 * d2);
            acc = (j < nmax) ? acc + s : acc;   // select, don't scale
        }
    }

    // ---------- block reduction ----------
    const float wsum = wave_reduce(acc);
    if ((t & 63) == 0) red[t >> 6] = wsum;
    __syncthreads();
    if (t == 0) {
        partials[blockIdx.x + TX * (blockIdx.y + TY * blockIdx.z)] =
            red[0] + red[1] + red[2] + red[3];
    }
}

__global__ __launch_bounds__(1024) void ssim_finalize(const float* __restrict__ partials,
                                                      float* __restrict__ out) {
    __shared__ double red[1024];
    const int t = threadIdx.x;
    double s = 0.0;
    for (int i = t; i < NBLK; i += 1024) s += (double)partials[i];
    red[t] = s;
    __syncthreads();
#pragma unroll
    for (int off = 512; off > 0; off >>= 1) {
        if (t < off) red[t] += red[t + off];
        __syncthreads();
    }
    if (t == 0) out[0] = (float)(red[0] / ((double)NIMG * OH * OW));
}

extern "C" void kernel_launch(void* const* d_in, const int* in_sizes, int n_in,
                              void* d_out, int out_size, void* d_ws, size_t ws_size,
                              hipStream_t stream) {
    const float* pred = (const float*)d_in[0];
    const float* act  = (const float*)d_in[1];
    float* partials = (float*)d_ws;              // NBLK floats, fully overwritten each call
    dim3 grid(TX, TY, NIMG);
    ssim_main<<<grid, 256, 0, stream>>>(pred, act, partials);
    ssim_finalize<<<1, 1024, 0, stream>>>(partials, (float*)d_out);
}